// Round 17
// baseline (651.635 us; speedup 1.0000x reference)
//
#include <hip/hip_runtime.h>

typedef unsigned short u16t;
typedef __attribute__((ext_vector_type(8))) short bf8;
typedef __attribute__((ext_vector_type(4))) float f4;

#define DEV __device__ __forceinline__

DEV u16t f2b(float f){
  unsigned u = __float_as_uint(f);
  u = (u + 0x7fffu + ((u >> 16) & 1u)) >> 16;
  return (u16t)u;
}
DEV float b2f(u16t u){ return __uint_as_float(((unsigned)u) << 16); }
DEV float sigm(float x){ return 1.f / (1.f + __expf(-x)); }

typedef __attribute__((address_space(1))) const void gas1;
typedef __attribute__((address_space(3))) void las3;
DEV void gl_lds16(const void* g, void* l){
  __builtin_amdgcn_global_load_lds((gas1*)g, (las3*)l, 16, 0, 0);
}

// B=2, SEQ=4096, D_MODEL=2048, D_INNER=2048, D_STATE=128, D_XB=512, D_CONV=4
// NHEADS=16, HEADDIM=128, NKV=4, N_REP=4, CHUNK=256, CONV_DIM=3072, D_IN_PROJ=5136
constexpr int KDIM   = 2048;
constexpr int DPROJ  = 5136;
constexpr int BLROWS = 8192;
constexpr int NT32   = KDIM / 32;   // 64 K-tiles of BK=32
constexpr int N4A = BLROWS * 2048 / 4;   // 4,194,304
constexpr int N4B = DPROJ * 2048 / 4;    // 2,629,632
constexpr int N4C = 2048 * 2048 / 4;     // 1,048,576
constexpr int N4T = N4A + N4B + N4C;     // 7,872,512

#define MFMA16(a,b,c) __builtin_amdgcn_mfma_f32_16x16x32_bf16((a),(b),(c),0,0,0)

// ---------------------------------------------------------------- K0: fused f32->bf16 (all 3 tensors, 1 launch)
__global__ __launch_bounds__(256) void k_cvt3(const float* __restrict__ hs,
                                              const float* __restrict__ ipw,
                                              const float* __restrict__ opw,
                                              u16t* __restrict__ X16,
                                              u16t* __restrict__ Wp16,
                                              u16t* __restrict__ Wo16){
  int i = blockIdx.x * 256 + threadIdx.x;
  if (i >= N4T) return;
  const float4* src;
  ushort4* dst;
  if (i < N4A){
    src = (const float4*)hs + i;          dst = (ushort4*)X16 + i;
  } else if (i < N4A + N4B){
    int j = i - N4A;
    src = (const float4*)ipw + j;         dst = (ushort4*)Wp16 + j;
  } else {
    int j = i - N4A - N4B;
    src = (const float4*)opw + j;         dst = (ushort4*)Wo16 + j;
  }
  float4 v = *src;
  ushort4 o;
  o.x = f2b(v.x); o.y = f2b(v.y); o.z = f2b(v.z); o.w = f2b(v.w);
  *dst = o;
}

// ================================================================ 128x256 2-block/CU GEMM core
// ROUND-14/16 PROVEN VERSION (measured: ~215 us on in_proj, MfmaUtil 37.2%,
// Occupancy 38.4%, 0 bank conflicts, ~810 TF). All schedule variants
// (2ph/8ph/refined/4-deep) and occupancy variants (1/2/4 blk/CU) bracket this
// plateau — structural limit for source-level HIP on this harness.
template<bool NCLAMP>
DEV void gemm128(const u16t* __restrict__ Ag, const u16t* __restrict__ Wg,
                 char* lds, int m0, int n0, f4 (&acc)[4][4]){
  const int tid = threadIdx.x;
  const int lane = tid & 63, w = tid >> 6;
  const int lo = lane & 15, hi = lane >> 4;
  const int wm = w >> 2, wn = w & 3;
  const int srow = tid >> 2;
  const int scol = ((tid & 3) ^ ((tid >> 3) & 3)) << 3;
  const int sdst = w << 10;
#pragma unroll
  for (int i = 0; i < 4; ++i)
#pragma unroll
    for (int j = 0; j < 4; ++j) acc[i][j] = (f4){0.f, 0.f, 0.f, 0.f};

  auto STAGE_A = [&](int d, int t){
    gl_lds16(Ag + (size_t)(m0 + srow) * KDIM + (t << 5) + scol,
             lds + d * 24576 + sdst);
  };
  auto STAGE_B = [&](int d, int op, int t){
    int r = n0 + op * 128 + srow;
    if (NCLAMP && r > DPROJ - 1) r = DPROJ - 1;
    gl_lds16(Wg + (size_t)r * KDIM + (t << 5) + scol,
             lds + d * 24576 + 8192 + op * 8192 + sdst);
  };
  auto RD_A = [&](const char* Ab, bf8 (&afr)[4]){
#pragma unroll
    for (int f = 0; f < 4; ++f){
      int row = wm * 64 + f * 16 + lo;
      afr[f] = *(const bf8*)(Ab + ((row >> 1) << 7) + ((row & 1) << 6)
                                + (((hi ^ (row >> 1)) & 3) << 4));
    }
  };
  auto RD_B = [&](const char* Bb, bf8 (&bfr)[4]){
#pragma unroll
    for (int f = 0; f < 4; ++f){
      int row = wn * 64 + f * 16 + lo;
      bfr[f] = *(const bf8*)(Bb + ((row >> 1) << 7) + ((row & 1) << 6)
                                + (((hi ^ (row >> 1)) & 3) << 4));
    }
  };

  STAGE_A(0, 0); STAGE_B(0, 0, 0); STAGE_B(0, 1, 0);
  asm volatile("s_waitcnt vmcnt(0)" ::: "memory");
  __builtin_amdgcn_s_barrier();

  for (int t = 0; t < NT32; ++t){
    const int d = t & 1, dn = d ^ 1;
    const char* Ab = lds + d * 24576;
    const char* Bb = Ab + 8192;
    bf8 afr[4], bfr[4];
    RD_B(Bb, bfr); RD_A(Ab, afr);
    if (t + 1 < NT32){ STAGE_A(dn, t + 1); STAGE_B(dn, 0, t + 1); STAGE_B(dn, 1, t + 1); }
    __builtin_amdgcn_s_setprio(1);
#pragma unroll
    for (int f = 0; f < 4; ++f)
#pragma unroll
      for (int n = 0; n < 4; ++n)
        acc[f][n] = MFMA16(afr[f], bfr[n], acc[f][n]);
    __builtin_amdgcn_s_setprio(0);
    asm volatile("s_waitcnt vmcnt(0)" ::: "memory");
    __builtin_amdgcn_s_barrier();
  }
}

// ---------------------------------------------------------------- K1: in_proj GEMM
// grid 1344 linear (21 n x 64 m), XCD-swizzled (1344 = 8*168 exact).
__global__ __launch_bounds__(512, 2) void k_gemm_in(const u16t* __restrict__ Ag,
                                                    const u16t* __restrict__ Wg,
                                                    u16t* __restrict__ z16,
                                                    u16t* __restrict__ xbc16,
                                                    float* __restrict__ dtraw){
  __shared__ __align__(16) char lds[49152];
  int id = blockIdx.x;
  int orig = (id & 7) * 168 + (id >> 3);
  int bx = orig % 21, by = orig / 21;
  const int m0 = by << 7, n0 = bx << 8;
  f4 acc[4][4];
  gemm128<true>(Ag, Wg, lds, m0, n0, acc);
  const int tid = threadIdx.x;
  const int lane = tid & 63, w = tid >> 6;
  const int lo = lane & 15, hi = lane >> 4;
  const int wm = w >> 2, wn = w & 3;
#pragma unroll
  for (int fm = 0; fm < 4; ++fm)
#pragma unroll
    for (int fn = 0; fn < 4; ++fn){
      int col = n0 + wn * 64 + fn * 16 + lo;
#pragma unroll
      for (int i = 0; i < 4; ++i){
        int r = m0 + wm * 64 + fm * 16 + hi * 4 + i;
        float v = acc[fm][fn][i];
        if (col < 2048)       z16[(size_t)r * 2048 + col] = f2b(v);
        else if (col < 5120)  xbc16[(size_t)r * 3072 + (col - 2048)] = f2b(v);
        else if (col < 5136)  dtraw[(size_t)r * 16 + (col - 5120)] = v;
      }
    }
}

// ---------------------------------------------------------------- K9: out_proj GEMM
// grid 512 linear (8 n x 64 m), XCD-swizzled (512 = 8*64 exact).
__global__ __launch_bounds__(512, 2) void k_gemm_out(const u16t* __restrict__ Ag,
                                                     const u16t* __restrict__ Wg,
                                                     float* __restrict__ C){
  __shared__ __align__(16) char lds[49152];
  int id = blockIdx.x;
  int orig = (id & 7) * 64 + (id >> 3);
  int bx = orig % 8, by = orig / 8;
  const int m0 = by << 7, n0 = bx << 8;
  f4 acc[4][4];
  gemm128<false>(Ag, Wg, lds, m0, n0, acc);
  const int tid = threadIdx.x;
  const int lane = tid & 63, w = tid >> 6;
  const int lo = lane & 15, hi = lane >> 4;
  const int wm = w >> 2, wn = w & 3;
#pragma unroll
  for (int fm = 0; fm < 4; ++fm)
#pragma unroll
    for (int fn = 0; fn < 4; ++fn){
      int col = n0 + wn * 64 + fn * 16 + lo;
#pragma unroll
      for (int i = 0; i < 4; ++i){
        int r = m0 + wm * 64 + fm * 16 + hi * 4 + i;
        C[(size_t)r * 2048 + col] = acc[fm][fn][i];
      }
    }
}

// ---------------------------------------------------------------- K2: conv + silu (rolling window, 32-row chunks)
__global__ __launch_bounds__(256) void k_conv(const u16t* __restrict__ xbc,
                                              const float* __restrict__ cw,
                                              const float* __restrict__ cb,
                                              u16t* __restrict__ xf16,
                                              u16t* __restrict__ Bg,
                                              u16t* __restrict__ Cgb){
  int ch = blockIdx.x * 1024 + threadIdx.x * 4;
  int b  = blockIdx.z;
  int l0 = blockIdx.y * 32;
  float4 cbv = *(const float4*)(cb + ch);
  float4 w0 = *(const float4*)(cw + ch * 4);
  float4 w1 = *(const float4*)(cw + ch * 4 + 4);
  float4 w2 = *(const float4*)(cw + ch * 4 + 8);
  float4 w3 = *(const float4*)(cw + ch * 4 + 12);
  const u16t* rowp = xbc + ((size_t)(b * 4096 + l0)) * 3072 + ch;
  float4 p3 = {0.f,0.f,0.f,0.f}, p2 = p3, p1 = p3;
  if (l0 > 0){
    ushort4 v;
    v = *(const ushort4*)(rowp - 3 * 3072); p3 = {b2f(v.x), b2f(v.y), b2f(v.z), b2f(v.w)};
    v = *(const ushort4*)(rowp - 2 * 3072); p2 = {b2f(v.x), b2f(v.y), b2f(v.z), b2f(v.w)};
    v = *(const ushort4*)(rowp - 1 * 3072); p1 = {b2f(v.x), b2f(v.y), b2f(v.z), b2f(v.w)};
  }
  for (int i = 0; i < 32; ++i){
    ushort4 v = *(const ushort4*)rowp;
    float4 cur = {b2f(v.x), b2f(v.y), b2f(v.z), b2f(v.w)};
    float a0 = cbv.x + p3.x * w0.x + p2.x * w0.y + p1.x * w0.z + cur.x * w0.w;
    float a1 = cbv.y + p3.y * w1.x + p2.y * w1.y + p1.y * w1.z + cur.y * w1.w;
    float a2 = cbv.z + p3.z * w2.x + p2.z * w2.y + p1.z * w2.z + cur.z * w2.w;
    float a3 = cbv.w + p3.w * w3.x + p2.w * w3.y + p1.w * w3.z + cur.w * w3.w;
    ushort4 o;
    o.x = f2b(a0 * sigm(a0)); o.y = f2b(a1 * sigm(a1));
    o.z = f2b(a2 * sigm(a2)); o.w = f2b(a3 * sigm(a3));
    size_t bl = (size_t)b * 4096 + l0 + i;
    if (ch < 512)       *(ushort4*)(xf16 + bl * 512 + ch) = o;
    else if (ch < 1024) *(ushort4*)(Bg + bl * 512 + (ch - 512)) = o;
    else                *(ushort4*)(Cgb + bl * 2048 + (ch - 1024)) = o;
    p3 = p2; p2 = p1; p1 = cur;
    rowp += 3072;
  }
}

// ---------------------------------------------------------------- K4: dt softplus + chunk cumsum (fused)
__global__ __launch_bounds__(256) void k_prep(const float* __restrict__ dtraw,
                                              const float* __restrict__ dtb,
                                              const float* __restrict__ alog,
                                              float* __restrict__ dtv,
                                              float* __restrict__ Acs,
                                              float* __restrict__ dstv,
                                              float* __restrict__ cdec){
  int c = blockIdx.x, h = blockIdx.y, b = blockIdx.z;
  int tid = threadIdx.x;
  int bhc = (b * 16 + h) * 16 + c;
  __shared__ float sb_[2][256];
  size_t bl = (size_t)b * 4096 + c * 256 + tid;
  float x = dtraw[bl * 16 + h] + dtb[h];
  float sp = (x > 15.f) ? x : log1pf(__expf(x));
  dtv[((size_t)(b * 16 + h)) * 4096 + c * 256 + tid] = sp;
  float An = -__expf(alog[h]);
  sb_[0][tid] = sp * An;
  __syncthreads();
  int src = 0;
  for (int off = 1; off < 256; off <<= 1){
    float v = sb_[src][tid];
    if (tid >= off) v += sb_[src][tid - off];
    sb_[src ^ 1][tid] = v;
    __syncthreads();
    src ^= 1;
  }
  float a = sb_[src][tid];
  float ae = sb_[src][255];
  Acs[(size_t)bhc * 256 + tid]  = a;
  dstv[(size_t)bhc * 256 + tid] = __expf(ae - a);
  if (tid == 0) cdec[bhc] = __expf(ae);
}

// ---------------------------------------------------------------- K5: repack transposes
__global__ __launch_bounds__(256, 4) void k_repack(const u16t* __restrict__ xf16,
                                                   const float* __restrict__ dtv,
                                                   const u16t* __restrict__ Bg,
                                                   u16t* __restrict__ xdtT,
                                                   u16t* __restrict__ BgT){
  int c = blockIdx.x, h = blockIdx.y, b = blockIdx.z;
  int tid = threadIdx.x;
  int bhc = (b * 16 + h) * 16 + c;
  int kv = h >> 2;
  __shared__ float tile[128][65];
  for (int st = 0; st < 4; ++st){
#pragma unroll
    for (int i = 0; i < 32; ++i){
      int idx = i * 256 + tid;
      int sl = idx >> 7, p = idx & 127;
      int l = c * 256 + st * 64 + sl;
      size_t bl = (size_t)b * 4096 + l;
      tile[p][sl] = b2f(xf16[bl * 512 + kv * 128 + p]) * dtv[((size_t)(b * 16 + h)) * 4096 + l];
    }
    __syncthreads();
#pragma unroll
    for (int i = 0; i < 32; ++i){
      int idx = i * 256 + tid;
      int p = idx >> 6, sl = idx & 63;
      xdtT[(size_t)bhc * 32768 + p * 256 + st * 64 + sl] = f2b(tile[p][sl]);
    }
    __syncthreads();
  }
  if (h < 4){
    for (int st = 0; st < 4; ++st){
#pragma unroll
      for (int i = 0; i < 32; ++i){
        int idx = i * 256 + tid;
        int sl = idx >> 7, n = idx & 127;
        size_t bl = (size_t)b * 4096 + c * 256 + st * 64 + sl;
        tile[n][sl] = (float)Bg[bl * 512 + h * 128 + n];
      }
      __syncthreads();
#pragma unroll
      for (int i = 0; i < 32; ++i){
        int idx = i * 256 + tid;
        int n = idx >> 6, sl = idx & 63;
        BgT[((size_t)(b * 4 + h) * 128 + n) * 4096 + c * 256 + st * 64 + sl] = (u16t)tile[n][sl];
      }
      __syncthreads();
    }
  }
}

// ---------------------------------------------------------------- K6: chunk states
__global__ __launch_bounds__(256, 3) void k_states(const u16t* __restrict__ xdtT,
                                                   const float* __restrict__ dstv,
                                                   const u16t* __restrict__ BgT,
                                                   u16t* __restrict__ states16){
  int c = blockIdx.x, h = blockIdx.y, b = blockIdx.z;
  int tid = threadIdx.x, lane = tid & 63, w = tid >> 6;
  int lo = lane & 15, hi = lane >> 4;
  int bhc = (b * 16 + h) * 16 + c;
  int kv = h >> 2;
  f4 zero = {0.f, 0.f, 0.f, 0.f};
  f4 acc[2][8];
#pragma unroll
  for (int i = 0; i < 2; ++i)
#pragma unroll
    for (int j = 0; j < 8; ++j) acc[i][j] = zero;
#pragma unroll
  for (int kk = 0; kk < 8; ++kk){
    f4 d0 = *(const f4*)(dstv + (size_t)bhc * 256 + kk * 32 + hi * 8);
    f4 d1 = *(const f4*)(dstv + (size_t)bhc * 256 + kk * 32 + hi * 8 + 4);
    bf8 af[2];
#pragma unroll
    for (int pr = 0; pr < 2; ++pr){
      bf8 a = *(const bf8*)(xdtT + (size_t)bhc * 32768 + (w * 32 + pr * 16 + lo) * 256 + kk * 32 + hi * 8);
      bf8 ad;
#pragma unroll
      for (int j = 0; j < 4; ++j){
        ad[j]     = (short)f2b(b2f((u16t)a[j]) * d0[j]);
        ad[4 + j] = (short)f2b(b2f((u16t)a[4 + j]) * d1[j]);
      }
      af[pr] = ad;
    }
    bf8 bb[8];
#pragma unroll
    for (int nb = 0; nb < 8; ++nb)
      bb[nb] = *(const bf8*)(BgT + ((size_t)(b * 4 + kv) * 128 + nb * 16 + lo) * 4096 + c * 256 + kk * 32 + hi * 8);
#pragma unroll
    for (int pr = 0; pr < 2; ++pr)
#pragma unroll
      for (int nb = 0; nb < 8; ++nb)
        acc[pr][nb] = MFMA16(af[pr], bb[nb], acc[pr][nb]);
  }
#pragma unroll
  for (int pr = 0; pr < 2; ++pr)
#pragma unroll
    for (int nb = 0; nb < 8; ++nb)
#pragma unroll
      for (int i = 0; i < 4; ++i)
        states16[(size_t)bhc * 16384 + (w * 32 + pr * 16 + hi * 4 + i) * 128 + nb * 16 + lo]
          = f2b(acc[pr][nb][i]);
}

// ---------------------------------------------------------------- K7: inter-chunk scan (16x parallel)
__global__ __launch_bounds__(256) void k_scan(const u16t* __restrict__ states16,
                                              const float* __restrict__ cdec,
                                              u16t* __restrict__ prevb){
  int h = blockIdx.x, b = blockIdx.y, sl = blockIdx.z;
  int tid = threadIdx.x;
  int bh = b * 16 + h;
  float carry[4];
#pragma unroll
  for (int i = 0; i < 4; ++i) carry[i] = 0.f;
  for (int c = 0; c < 16; ++c){
    size_t base = ((size_t)bh * 16 + c) * 16384 + sl * 1024;
    float cd = cdec[bh * 16 + c];
#pragma unroll
    for (int i = 0; i < 4; ++i){
      size_t idx = base + i * 256 + tid;
      prevb[idx] = f2b(carry[i]);
      carry[i] = carry[i] * cd + b2f(states16[idx]);
    }
  }
}

// ---------------------------------------------------------------- K8: Y_off + Y_diag + gate + RMSNorm
// (round-14 32-row-wave version; +launch_bounds(256,3) occupancy hint)
__global__ __launch_bounds__(256, 3) void k_fin(const u16t* __restrict__ Cg,
                                                const u16t* __restrict__ Bg,
                                                const u16t* __restrict__ xdtT,
                                                const u16t* __restrict__ prevb,
                                                const float* __restrict__ Acs,
                                                const u16t* __restrict__ z16,
                                                const u16t* __restrict__ xf16,
                                                const float* __restrict__ Dp,
                                                const float* __restrict__ nw,
                                                u16t* __restrict__ yn){
  int c2 = blockIdx.x, h = blockIdx.y, b = blockIdx.z;
  int c = c2 >> 1, half = c2 & 1;
  int tid = threadIdx.x, lane = tid & 63, w = tid >> 6;
  int lo = lane & 15, hi = lane >> 4;
  int bhc = (b * 16 + h) * 16 + c;
  int kv = h >> 2;
  int blbase = b * 4096 + c * 256;
  const int lbase = half * 128 + w * 32;
  const int jmax = half * 4 + w;
  __shared__ float AcsS[256];
  __shared__ __align__(16) char Gb[4][2048];
  AcsS[tid] = Acs[(size_t)bhc * 256 + tid];
  __syncthreads();
  char* gw = Gb[w];
  f4 accY[2][8];
#pragma unroll
  for (int i = 0; i < 2; ++i)
#pragma unroll
    for (int j = 0; j < 8; ++j) accY[i][j] = (f4){0.f, 0.f, 0.f, 0.f};
  float eav[2];
#pragma unroll
  for (int mb = 0; mb < 2; ++mb)
    eav[mb] = __expf(AcsS[lbase + mb * 16 + lo]);
#pragma unroll
  for (int kk = 0; kk < 4; ++kk){
    bf8 af[2], bb[8];
#pragma unroll
    for (int mb = 0; mb < 2; ++mb){
      int l = lbase + mb * 16 + lo;
      bf8 cr = *(const bf8*)(Cg + (size_t)(blbase + l) * 2048 + h * 128 + kk * 32 + hi * 8);
      bf8 cs;
#pragma unroll
      for (int j = 0; j < 8; ++j) cs[j] = (short)f2b(b2f((u16t)cr[j]) * eav[mb]);
      af[mb] = cs;
    }
#pragma unroll
    for (int pb = 0; pb < 8; ++pb)
      bb[pb] = *(const bf8*)(prevb + (size_t)bhc * 16384 + (pb * 16 + lo) * 128 + kk * 32 + hi * 8);
#pragma unroll
    for (int mb = 0; mb < 2; ++mb)
#pragma unroll
      for (int pb = 0; pb < 8; ++pb)
        accY[mb][pb] = MFMA16(af[mb], bb[pb], accY[mb][pb]);
  }
  for (int sb = 0; sb <= jmax; ++sb){
    f4 g[2][2];
#pragma unroll
    for (int i = 0; i < 2; ++i)
#pragma unroll
      for (int j = 0; j < 2; ++j) g[i][j] = (f4){0.f, 0.f, 0.f, 0.f};
#pragma unroll
    for (int kk = 0; kk < 4; ++kk){
      bf8 af[2], bb[2];
#pragma unroll
      for (int mb = 0; mb < 2; ++mb)
        af[mb] = *(const bf8*)(Cg + (size_t)(blbase + lbase + mb * 16 + lo) * 2048 + h * 128 + kk * 32 + hi * 8);
#pragma unroll
      for (int nb = 0; nb < 2; ++nb)
        bb[nb] = *(const bf8*)(Bg + (size_t)(blbase + sb * 32 + nb * 16 + lo) * 512 + kv * 128 + kk * 32 + hi * 8);
#pragma unroll
      for (int mb = 0; mb < 2; ++mb)
#pragma unroll
        for (int nb = 0; nb < 2; ++nb)
          g[mb][nb] = MFMA16(af[mb], bb[nb], g[mb][nb]);
    }
#pragma unroll
    for (int mb = 0; mb < 2; ++mb)
#pragma unroll
      for (int nb = 0; nb < 2; ++nb)
#pragma unroll
        for (int i = 0; i < 4; ++i){
          int lrow = lbase + mb * 16 + hi * 4 + i;
          int scol = sb * 32 + nb * 16 + lo;
          float v = g[mb][nb][i];
          v = (scol <= lrow) ? v * __expf(AcsS[lrow] - AcsS[scol]) : 0.f;
          int rl = mb * 16 + hi * 4 + i;
          int col = nb * 16 + lo;
          int off = ((rl >> 1) << 7) + ((rl & 1) << 6)
                  + ((col << 1) ^ (((rl >> 1) & 3) << 4));
          *(u16t*)(gw + off) = f2b(v);
        }
    bf8 a2[2], b2[8];
#pragma unroll
    for (int mb = 0; mb < 2; ++mb){
      int rl = mb * 16 + lo;
      a2[mb] = *(const bf8*)(gw + ((rl >> 1) << 7) + ((rl & 1) << 6)
                                + ((hi << 4) ^ (((rl >> 1) & 3) << 4)));
    }
#pragma unroll
    for (int pb = 0; pb < 8; ++pb)
      b2[pb] = *(const bf8*)(xdtT + (size_t)bhc * 32768 + (pb * 16 + lo) * 256 + sb * 32 + hi * 8);
#pragma unroll
    for (int mb = 0; mb < 2; ++mb)
#pragma unroll
      for (int pb = 0; pb < 8; ++pb)
        accY[mb][pb] = MFMA16(a2[mb], b2[pb], accY[mb][pb]);
  }
  float Dh = Dp[h];
#pragma unroll
  for (int mb = 0; mb < 2; ++mb){
#pragma unroll
    for (int i = 0; i < 4; ++i){
      int lrow = lbase + mb * 16 + hi * 4 + i;
      size_t bl = (size_t)blbase + lrow;
      float gv[8];
      float ss = 0.f;
#pragma unroll
      for (int pb = 0; pb < 8; ++pb){
        int p = pb * 16 + lo;
        float y = accY[mb][pb][i] + Dh * b2f(xf16[bl * 512 + kv * 128 + p]);
        float z = b2f(z16[bl * 2048 + h * 128 + p]);
        float g = y * z * sigm(z);
        gv[pb] = g;
        ss += g * g;
      }
      ss += __shfl_xor(ss, 1);
      ss += __shfl_xor(ss, 2);
      ss += __shfl_xor(ss, 4);
      ss += __shfl_xor(ss, 8);
      float rstd = rsqrtf(ss * (1.f / 128.f) + 1e-5f);
#pragma unroll
      for (int pb = 0; pb < 8; ++pb){
        int p = pb * 16 + lo;
        yn[bl * 2048 + h * 128 + p] = f2b(gv[pb] * rstd * nw[h * 128 + p]);
      }
    }
  }
}

// ---------------------------------------------------------------- launch
extern "C" void kernel_launch(void* const* d_in, const int* in_sizes, int n_in,
                              void* d_out, int out_size, void* d_ws, size_t ws_size,
                              hipStream_t stream){
  const float* hs   = (const float*)d_in[0];
  const float* ipw  = (const float*)d_in[1];
  const float* cw   = (const float*)d_in[2];
  const float* cb   = (const float*)d_in[3];
  const float* dtb  = (const float*)d_in[4];
  const float* alog = (const float*)d_in[5];
  const float* Dp   = (const float*)d_in[6];
  const float* nw   = (const float*)d_in[7];
  const float* opw  = (const float*)d_in[8];
  float* out = (float*)d_out;

  char* base = (char*)d_ws;
  size_t o = 0;
  auto take = [&](size_t n) -> size_t { size_t r = o; o += (n + 255) & ~(size_t)255; return r; };

  // Region A: X16 (K0..K1) -> states16 + prevb (K6..K8)
  size_t offA = take(33554432);
  u16t* X16      = (u16t*)(base + offA);
  u16t* states16 = (u16t*)(base + offA);
  u16t* prevb    = (u16t*)(base + offA + 16777216);
  // Region B: Wp16 (K0..K1) -> BgT + dtv + Acs + dstv + cdec (K3..K8)
  size_t offB = take(21037056);
  u16t*  Wp16 = (u16t*)(base + offB);
  u16t*  BgT  = (u16t*)(base + offB);
  float* dtv  = (float*)(base + offB + 8388608);
  float* Acs  = (float*)(base + offB + 8912896);
  float* dstv = (float*)(base + offB + 9437184);
  float* cdec = (float*)(base + offB + 9961472);
  u16t*  Wo16 = (u16t*)(base + take(8388608));
  u16t*  z16  = (u16t*)(base + take(33554432));
  // Region C: xbc16 (K1..K2) -> yn16 (K8..K9)
  size_t offC = take(50331648);
  u16t* xbc16 = (u16t*)(base + offC);
  u16t* yn16  = (u16t*)(base + offC);
  float* dtraw = (float*)(base + take(524288));
  u16t*  xf16  = (u16t*)(base + take(8388608));
  u16t*  Bg    = (u16t*)(base + take(8388608));
  u16t*  Cgb   = (u16t*)(base + take(33554432));
  u16t*  xdtT  = (u16t*)(base + take(33554432));

  if (ws_size < o) return;  // budget guard

  k_cvt3<<<(N4T + 255) / 256, 256, 0, stream>>>(hs, ipw, opw, X16, Wp16, Wo16);
  k_gemm_in<<<1344, 512, 0, stream>>>(X16, Wp16, z16, xbc16, dtraw);
  k_conv<<<dim3(3, 128, 2), 256, 0, stream>>>(xbc16, cw, cb, xf16, Bg, Cgb);
  k_prep<<<dim3(16, 16, 2), 256, 0, stream>>>(dtraw, dtb, alog, dtv, Acs, dstv, cdec);
  k_repack<<<dim3(16, 16, 2), 256, 0, stream>>>(xf16, dtv, Bg, xdtT, BgT);
  k_states<<<dim3(16, 16, 2), 256, 0, stream>>>(xdtT, dstv, BgT, states16);
  k_scan<<<dim3(16, 2, 16), 256, 0, stream>>>(states16, cdec, prevb);
  k_fin<<<dim3(32, 16, 2), 256, 0, stream>>>(Cgb, Bg, xdtT, prevb, Acs, z16, xf16, Dp, nw, yn16);
  k_gemm_out<<<512, 512, 0, stream>>>(yn16, Wo16, out);
}

// Round 18
// 523.581 us; speedup vs baseline: 1.2446x; 1.2446x over previous
//
#include <hip/hip_runtime.h>

typedef unsigned short u16t;
typedef __attribute__((ext_vector_type(8))) short bf8;
typedef __attribute__((ext_vector_type(4))) float f4;

#define DEV __device__ __forceinline__

DEV u16t f2b(float f){
  unsigned u = __float_as_uint(f);
  u = (u + 0x7fffu + ((u >> 16) & 1u)) >> 16;
  return (u16t)u;
}
DEV float b2f(u16t u){ return __uint_as_float(((unsigned)u) << 16); }
DEV float sigm(float x){ return 1.f / (1.f + __expf(-x)); }

typedef __attribute__((address_space(1))) const void gas1;
typedef __attribute__((address_space(3))) void las3;
DEV void gl_lds16(const void* g, void* l){
  __builtin_amdgcn_global_load_lds((gas1*)g, (las3*)l, 16, 0, 0);
}

// B=2, SEQ=4096, D_MODEL=2048, D_INNER=2048, D_STATE=128, D_XB=512, D_CONV=4
// NHEADS=16, HEADDIM=128, NKV=4, N_REP=4, CHUNK=256, CONV_DIM=3072, D_IN_PROJ=5136
constexpr int KDIM   = 2048;
constexpr int DPROJ  = 5136;
constexpr int BLROWS = 8192;
constexpr int NT32   = KDIM / 32;   // 64 K-tiles of BK=32

#define MFMA16(a,b,c) __builtin_amdgcn_mfma_f32_16x16x32_bf16((a),(b),(c),0,0,0)

// ---------------------------------------------------------------- K0: f32->bf16
__global__ __launch_bounds__(256) void k_cvt(const float* __restrict__ src,
                                             u16t* __restrict__ dst, int n4){
  int i = blockIdx.x * 256 + threadIdx.x;
  if (i < n4){
    float4 v = ((const float4*)src)[i];
    ushort4 o;
    o.x = f2b(v.x); o.y = f2b(v.y); o.z = f2b(v.z); o.w = f2b(v.w);
    ((ushort4*)dst)[i] = o;
  }
}

// ================================================================ 128x256 2-block/CU GEMM core
// ROUND-14/16 PROVEN VERSION (measured: ~215 us on in_proj, MfmaUtil 37.2%,
// Occupancy 38.4%, 0 bank conflicts, ~810 TF). Round-17's launch_bounds hints
// on SSD kernels regressed (+127 us — register-cap spills, round-12 failure
// mode) — reverted to this exact round-16 configuration (524 us best).
template<bool NCLAMP>
DEV void gemm128(const u16t* __restrict__ Ag, const u16t* __restrict__ Wg,
                 char* lds, int m0, int n0, f4 (&acc)[4][4]){
  const int tid = threadIdx.x;
  const int lane = tid & 63, w = tid >> 6;
  const int lo = lane & 15, hi = lane >> 4;
  const int wm = w >> 2, wn = w & 3;
  const int srow = tid >> 2;
  const int scol = ((tid & 3) ^ ((tid >> 3) & 3)) << 3;
  const int sdst = w << 10;
#pragma unroll
  for (int i = 0; i < 4; ++i)
#pragma unroll
    for (int j = 0; j < 4; ++j) acc[i][j] = (f4){0.f, 0.f, 0.f, 0.f};

  auto STAGE_A = [&](int d, int t){
    gl_lds16(Ag + (size_t)(m0 + srow) * KDIM + (t << 5) + scol,
             lds + d * 24576 + sdst);
  };
  auto STAGE_B = [&](int d, int op, int t){
    int r = n0 + op * 128 + srow;
    if (NCLAMP && r > DPROJ - 1) r = DPROJ - 1;
    gl_lds16(Wg + (size_t)r * KDIM + (t << 5) + scol,
             lds + d * 24576 + 8192 + op * 8192 + sdst);
  };
  auto RD_A = [&](const char* Ab, bf8 (&afr)[4]){
#pragma unroll
    for (int f = 0; f < 4; ++f){
      int row = wm * 64 + f * 16 + lo;
      afr[f] = *(const bf8*)(Ab + ((row >> 1) << 7) + ((row & 1) << 6)
                                + (((hi ^ (row >> 1)) & 3) << 4));
    }
  };
  auto RD_B = [&](const char* Bb, bf8 (&bfr)[4]){
#pragma unroll
    for (int f = 0; f < 4; ++f){
      int row = wn * 64 + f * 16 + lo;
      bfr[f] = *(const bf8*)(Bb + ((row >> 1) << 7) + ((row & 1) << 6)
                                + (((hi ^ (row >> 1)) & 3) << 4));
    }
  };

  STAGE_A(0, 0); STAGE_B(0, 0, 0); STAGE_B(0, 1, 0);
  asm volatile("s_waitcnt vmcnt(0)" ::: "memory");
  __builtin_amdgcn_s_barrier();

  for (int t = 0; t < NT32; ++t){
    const int d = t & 1, dn = d ^ 1;
    const char* Ab = lds + d * 24576;
    const char* Bb = Ab + 8192;
    bf8 afr[4], bfr[4];
    RD_B(Bb, bfr); RD_A(Ab, afr);
    if (t + 1 < NT32){ STAGE_A(dn, t + 1); STAGE_B(dn, 0, t + 1); STAGE_B(dn, 1, t + 1); }
    __builtin_amdgcn_s_setprio(1);
#pragma unroll
    for (int f = 0; f < 4; ++f)
#pragma unroll
      for (int n = 0; n < 4; ++n)
        acc[f][n] = MFMA16(afr[f], bfr[n], acc[f][n]);
    __builtin_amdgcn_s_setprio(0);
    asm volatile("s_waitcnt vmcnt(0)" ::: "memory");
    __builtin_amdgcn_s_barrier();
  }
}

// ---------------------------------------------------------------- K1: in_proj GEMM
// grid 1344 linear (21 n x 64 m), XCD-swizzled (1344 = 8*168 exact).
__global__ __launch_bounds__(512, 2) void k_gemm_in(const u16t* __restrict__ Ag,
                                                    const u16t* __restrict__ Wg,
                                                    u16t* __restrict__ z16,
                                                    u16t* __restrict__ xbc16,
                                                    float* __restrict__ dtraw){
  __shared__ __align__(16) char lds[49152];
  int id = blockIdx.x;
  int orig = (id & 7) * 168 + (id >> 3);
  int bx = orig % 21, by = orig / 21;
  const int m0 = by << 7, n0 = bx << 8;
  f4 acc[4][4];
  gemm128<true>(Ag, Wg, lds, m0, n0, acc);
  const int tid = threadIdx.x;
  const int lane = tid & 63, w = tid >> 6;
  const int lo = lane & 15, hi = lane >> 4;
  const int wm = w >> 2, wn = w & 3;
#pragma unroll
  for (int fm = 0; fm < 4; ++fm)
#pragma unroll
    for (int fn = 0; fn < 4; ++fn){
      int col = n0 + wn * 64 + fn * 16 + lo;
#pragma unroll
      for (int i = 0; i < 4; ++i){
        int r = m0 + wm * 64 + fm * 16 + hi * 4 + i;
        float v = acc[fm][fn][i];
        if (col < 2048)       z16[(size_t)r * 2048 + col] = f2b(v);
        else if (col < 5120)  xbc16[(size_t)r * 3072 + (col - 2048)] = f2b(v);
        else if (col < 5136)  dtraw[(size_t)r * 16 + (col - 5120)] = v;
      }
    }
}

// ---------------------------------------------------------------- K9: out_proj GEMM
// grid 512 linear (8 n x 64 m), XCD-swizzled (512 = 8*64 exact).
__global__ __launch_bounds__(512, 2) void k_gemm_out(const u16t* __restrict__ Ag,
                                                     const u16t* __restrict__ Wg,
                                                     float* __restrict__ C){
  __shared__ __align__(16) char lds[49152];
  int id = blockIdx.x;
  int orig = (id & 7) * 64 + (id >> 3);
  int bx = orig % 8, by = orig / 8;
  const int m0 = by << 7, n0 = bx << 8;
  f4 acc[4][4];
  gemm128<false>(Ag, Wg, lds, m0, n0, acc);
  const int tid = threadIdx.x;
  const int lane = tid & 63, w = tid >> 6;
  const int lo = lane & 15, hi = lane >> 4;
  const int wm = w >> 2, wn = w & 3;
#pragma unroll
  for (int fm = 0; fm < 4; ++fm)
#pragma unroll
    for (int fn = 0; fn < 4; ++fn){
      int col = n0 + wn * 64 + fn * 16 + lo;
#pragma unroll
      for (int i = 0; i < 4; ++i){
        int r = m0 + wm * 64 + fm * 16 + hi * 4 + i;
        C[(size_t)r * 2048 + col] = acc[fm][fn][i];
      }
    }
}

// ---------------------------------------------------------------- K2: conv + silu (rolling window, 32-row chunks)
__global__ __launch_bounds__(256) void k_conv(const u16t* __restrict__ xbc,
                                              const float* __restrict__ cw,
                                              const float* __restrict__ cb,
                                              u16t* __restrict__ xf16,
                                              u16t* __restrict__ Bg,
                                              u16t* __restrict__ Cgb){
  int ch = blockIdx.x * 1024 + threadIdx.x * 4;
  int b  = blockIdx.z;
  int l0 = blockIdx.y * 32;
  float4 cbv = *(const float4*)(cb + ch);
  float4 w0 = *(const float4*)(cw + ch * 4);
  float4 w1 = *(const float4*)(cw + ch * 4 + 4);
  float4 w2 = *(const float4*)(cw + ch * 4 + 8);
  float4 w3 = *(const float4*)(cw + ch * 4 + 12);
  const u16t* rowp = xbc + ((size_t)(b * 4096 + l0)) * 3072 + ch;
  float4 p3 = {0.f,0.f,0.f,0.f}, p2 = p3, p1 = p3;
  if (l0 > 0){
    ushort4 v;
    v = *(const ushort4*)(rowp - 3 * 3072); p3 = {b2f(v.x), b2f(v.y), b2f(v.z), b2f(v.w)};
    v = *(const ushort4*)(rowp - 2 * 3072); p2 = {b2f(v.x), b2f(v.y), b2f(v.z), b2f(v.w)};
    v = *(const ushort4*)(rowp - 1 * 3072); p1 = {b2f(v.x), b2f(v.y), b2f(v.z), b2f(v.w)};
  }
  for (int i = 0; i < 32; ++i){
    ushort4 v = *(const ushort4*)rowp;
    float4 cur = {b2f(v.x), b2f(v.y), b2f(v.z), b2f(v.w)};
    float a0 = cbv.x + p3.x * w0.x + p2.x * w0.y + p1.x * w0.z + cur.x * w0.w;
    float a1 = cbv.y + p3.y * w1.x + p2.y * w1.y + p1.y * w1.z + cur.y * w1.w;
    float a2 = cbv.z + p3.z * w2.x + p2.z * w2.y + p1.z * w2.z + cur.z * w2.w;
    float a3 = cbv.w + p3.w * w3.x + p2.w * w3.y + p1.w * w3.z + cur.w * w3.w;
    ushort4 o;
    o.x = f2b(a0 * sigm(a0)); o.y = f2b(a1 * sigm(a1));
    o.z = f2b(a2 * sigm(a2)); o.w = f2b(a3 * sigm(a3));
    size_t bl = (size_t)b * 4096 + l0 + i;
    if (ch < 512)       *(ushort4*)(xf16 + bl * 512 + ch) = o;
    else if (ch < 1024) *(ushort4*)(Bg + bl * 512 + (ch - 512)) = o;
    else                *(ushort4*)(Cgb + bl * 2048 + (ch - 1024)) = o;
    p3 = p2; p2 = p1; p1 = cur;
    rowp += 3072;
  }
}

// ---------------------------------------------------------------- K4: dt softplus + chunk cumsum (fused)
__global__ __launch_bounds__(256) void k_prep(const float* __restrict__ dtraw,
                                              const float* __restrict__ dtb,
                                              const float* __restrict__ alog,
                                              float* __restrict__ dtv,
                                              float* __restrict__ Acs,
                                              float* __restrict__ dstv,
                                              float* __restrict__ cdec){
  int c = blockIdx.x, h = blockIdx.y, b = blockIdx.z;
  int tid = threadIdx.x;
  int bhc = (b * 16 + h) * 16 + c;
  __shared__ float sb_[2][256];
  size_t bl = (size_t)b * 4096 + c * 256 + tid;
  float x = dtraw[bl * 16 + h] + dtb[h];
  float sp = (x > 15.f) ? x : log1pf(__expf(x));
  dtv[((size_t)(b * 16 + h)) * 4096 + c * 256 + tid] = sp;
  float An = -__expf(alog[h]);
  sb_[0][tid] = sp * An;
  __syncthreads();
  int src = 0;
  for (int off = 1; off < 256; off <<= 1){
    float v = sb_[src][tid];
    if (tid >= off) v += sb_[src][tid - off];
    sb_[src ^ 1][tid] = v;
    __syncthreads();
    src ^= 1;
  }
  float a = sb_[src][tid];
  float ae = sb_[src][255];
  Acs[(size_t)bhc * 256 + tid]  = a;
  dstv[(size_t)bhc * 256 + tid] = __expf(ae - a);
  if (tid == 0) cdec[bhc] = __expf(ae);
}

// ---------------------------------------------------------------- K5: repack transposes
__global__ __launch_bounds__(256) void k_repack(const u16t* __restrict__ xf16,
                                                const float* __restrict__ dtv,
                                                const u16t* __restrict__ Bg,
                                                u16t* __restrict__ xdtT,
                                                u16t* __restrict__ BgT){
  int c = blockIdx.x, h = blockIdx.y, b = blockIdx.z;
  int tid = threadIdx.x;
  int bhc = (b * 16 + h) * 16 + c;
  int kv = h >> 2;
  __shared__ float tile[128][65];
  for (int st = 0; st < 4; ++st){
#pragma unroll
    for (int i = 0; i < 32; ++i){
      int idx = i * 256 + tid;
      int sl = idx >> 7, p = idx & 127;
      int l = c * 256 + st * 64 + sl;
      size_t bl = (size_t)b * 4096 + l;
      tile[p][sl] = b2f(xf16[bl * 512 + kv * 128 + p]) * dtv[((size_t)(b * 16 + h)) * 4096 + l];
    }
    __syncthreads();
#pragma unroll
    for (int i = 0; i < 32; ++i){
      int idx = i * 256 + tid;
      int p = idx >> 6, sl = idx & 63;
      xdtT[(size_t)bhc * 32768 + p * 256 + st * 64 + sl] = f2b(tile[p][sl]);
    }
    __syncthreads();
  }
  if (h < 4){
    for (int st = 0; st < 4; ++st){
#pragma unroll
      for (int i = 0; i < 32; ++i){
        int idx = i * 256 + tid;
        int sl = idx >> 7, n = idx & 127;
        size_t bl = (size_t)b * 4096 + c * 256 + st * 64 + sl;
        tile[n][sl] = (float)Bg[bl * 512 + h * 128 + n];
      }
      __syncthreads();
#pragma unroll
      for (int i = 0; i < 32; ++i){
        int idx = i * 256 + tid;
        int n = idx >> 6, sl = idx & 63;
        BgT[((size_t)(b * 4 + h) * 128 + n) * 4096 + c * 256 + st * 64 + sl] = (u16t)tile[n][sl];
      }
      __syncthreads();
    }
  }
}

// ---------------------------------------------------------------- K6: chunk states
__global__ __launch_bounds__(256) void k_states(const u16t* __restrict__ xdtT,
                                                const float* __restrict__ dstv,
                                                const u16t* __restrict__ BgT,
                                                u16t* __restrict__ states16){
  int c = blockIdx.x, h = blockIdx.y, b = blockIdx.z;
  int tid = threadIdx.x, lane = tid & 63, w = tid >> 6;
  int lo = lane & 15, hi = lane >> 4;
  int bhc = (b * 16 + h) * 16 + c;
  int kv = h >> 2;
  f4 zero = {0.f, 0.f, 0.f, 0.f};
  f4 acc[2][8];
#pragma unroll
  for (int i = 0; i < 2; ++i)
#pragma unroll
    for (int j = 0; j < 8; ++j) acc[i][j] = zero;
#pragma unroll
  for (int kk = 0; kk < 8; ++kk){
    f4 d0 = *(const f4*)(dstv + (size_t)bhc * 256 + kk * 32 + hi * 8);
    f4 d1 = *(const f4*)(dstv + (size_t)bhc * 256 + kk * 32 + hi * 8 + 4);
    bf8 af[2];
#pragma unroll
    for (int pr = 0; pr < 2; ++pr){
      bf8 a = *(const bf8*)(xdtT + (size_t)bhc * 32768 + (w * 32 + pr * 16 + lo) * 256 + kk * 32 + hi * 8);
      bf8 ad;
#pragma unroll
      for (int j = 0; j < 4; ++j){
        ad[j]     = (short)f2b(b2f((u16t)a[j]) * d0[j]);
        ad[4 + j] = (short)f2b(b2f((u16t)a[4 + j]) * d1[j]);
      }
      af[pr] = ad;
    }
    bf8 bb[8];
#pragma unroll
    for (int nb = 0; nb < 8; ++nb)
      bb[nb] = *(const bf8*)(BgT + ((size_t)(b * 4 + kv) * 128 + nb * 16 + lo) * 4096 + c * 256 + kk * 32 + hi * 8);
#pragma unroll
    for (int pr = 0; pr < 2; ++pr)
#pragma unroll
      for (int nb = 0; nb < 8; ++nb)
        acc[pr][nb] = MFMA16(af[pr], bb[nb], acc[pr][nb]);
  }
#pragma unroll
  for (int pr = 0; pr < 2; ++pr)
#pragma unroll
    for (int nb = 0; nb < 8; ++nb)
#pragma unroll
      for (int i = 0; i < 4; ++i)
        states16[(size_t)bhc * 16384 + (w * 32 + pr * 16 + hi * 4 + i) * 128 + nb * 16 + lo]
          = f2b(acc[pr][nb][i]);
}

// ---------------------------------------------------------------- K7: inter-chunk scan (16x parallel)
__global__ __launch_bounds__(256) void k_scan(const u16t* __restrict__ states16,
                                              const float* __restrict__ cdec,
                                              u16t* __restrict__ prevb){
  int h = blockIdx.x, b = blockIdx.y, sl = blockIdx.z;
  int tid = threadIdx.x;
  int bh = b * 16 + h;
  float carry[4];
#pragma unroll
  for (int i = 0; i < 4; ++i) carry[i] = 0.f;
  for (int c = 0; c < 16; ++c){
    size_t base = ((size_t)bh * 16 + c) * 16384 + sl * 1024;
    float cd = cdec[bh * 16 + c];
#pragma unroll
    for (int i = 0; i < 4; ++i){
      size_t idx = base + i * 256 + tid;
      prevb[idx] = f2b(carry[i]);
      carry[i] = carry[i] * cd + b2f(states16[idx]);
    }
  }
}

// ---------------------------------------------------------------- K8: Y_off + Y_diag + gate + RMSNorm
// (round-14 32-row-wave version — measured good; NO launch_bounds min-waves hint)
__global__ __launch_bounds__(256) void k_fin(const u16t* __restrict__ Cg,
                                             const u16t* __restrict__ Bg,
                                             const u16t* __restrict__ xdtT,
                                             const u16t* __restrict__ prevb,
                                             const float* __restrict__ Acs,
                                             const u16t* __restrict__ z16,
                                             const u16t* __restrict__ xf16,
                                             const float* __restrict__ Dp,
                                             const float* __restrict__ nw,
                                             u16t* __restrict__ yn){
  int c2 = blockIdx.x, h = blockIdx.y, b = blockIdx.z;
  int c = c2 >> 1, half = c2 & 1;
  int tid = threadIdx.x, lane = tid & 63, w = tid >> 6;
  int lo = lane & 15, hi = lane >> 4;
  int bhc = (b * 16 + h) * 16 + c;
  int kv = h >> 2;
  int blbase = b * 4096 + c * 256;
  const int lbase = half * 128 + w * 32;
  const int jmax = half * 4 + w;
  __shared__ float AcsS[256];
  __shared__ __align__(16) char Gb[4][2048];
  AcsS[tid] = Acs[(size_t)bhc * 256 + tid];
  __syncthreads();
  char* gw = Gb[w];
  f4 accY[2][8];
#pragma unroll
  for (int i = 0; i < 2; ++i)
#pragma unroll
    for (int j = 0; j < 8; ++j) accY[i][j] = (f4){0.f, 0.f, 0.f, 0.f};
  float eav[2];
#pragma unroll
  for (int mb = 0; mb < 2; ++mb)
    eav[mb] = __expf(AcsS[lbase + mb * 16 + lo]);
#pragma unroll
  for (int kk = 0; kk < 4; ++kk){
    bf8 af[2], bb[8];
#pragma unroll
    for (int mb = 0; mb < 2; ++mb){
      int l = lbase + mb * 16 + lo;
      bf8 cr = *(const bf8*)(Cg + (size_t)(blbase + l) * 2048 + h * 128 + kk * 32 + hi * 8);
      bf8 cs;
#pragma unroll
      for (int j = 0; j < 8; ++j) cs[j] = (short)f2b(b2f((u16t)cr[j]) * eav[mb]);
      af[mb] = cs;
    }
#pragma unroll
    for (int pb = 0; pb < 8; ++pb)
      bb[pb] = *(const bf8*)(prevb + (size_t)bhc * 16384 + (pb * 16 + lo) * 128 + kk * 32 + hi * 8);
#pragma unroll
    for (int mb = 0; mb < 2; ++mb)
#pragma unroll
      for (int pb = 0; pb < 8; ++pb)
        accY[mb][pb] = MFMA16(af[mb], bb[pb], accY[mb][pb]);
  }
  for (int sb = 0; sb <= jmax; ++sb){
    f4 g[2][2];
#pragma unroll
    for (int i = 0; i < 2; ++i)
#pragma unroll
      for (int j = 0; j < 2; ++j) g[i][j] = (f4){0.f, 0.f, 0.f, 0.f};
#pragma unroll
    for (int kk = 0; kk < 4; ++kk){
      bf8 af[2], bb[2];
#pragma unroll
      for (int mb = 0; mb < 2; ++mb)
        af[mb] = *(const bf8*)(Cg + (size_t)(blbase + lbase + mb * 16 + lo) * 2048 + h * 128 + kk * 32 + hi * 8);
#pragma unroll
      for (int nb = 0; nb < 2; ++nb)
        bb[nb] = *(const bf8*)(Bg + (size_t)(blbase + sb * 32 + nb * 16 + lo) * 512 + kv * 128 + kk * 32 + hi * 8);
#pragma unroll
      for (int mb = 0; mb < 2; ++mb)
#pragma unroll
        for (int nb = 0; nb < 2; ++nb)
          g[mb][nb] = MFMA16(af[mb], bb[nb], g[mb][nb]);
    }
#pragma unroll
    for (int mb = 0; mb < 2; ++mb)
#pragma unroll
      for (int nb = 0; nb < 2; ++nb)
#pragma unroll
        for (int i = 0; i < 4; ++i){
          int lrow = lbase + mb * 16 + hi * 4 + i;
          int scol = sb * 32 + nb * 16 + lo;
          float v = g[mb][nb][i];
          v = (scol <= lrow) ? v * __expf(AcsS[lrow] - AcsS[scol]) : 0.f;
          int rl = mb * 16 + hi * 4 + i;
          int col = nb * 16 + lo;
          int off = ((rl >> 1) << 7) + ((rl & 1) << 6)
                  + ((col << 1) ^ (((rl >> 1) & 3) << 4));
          *(u16t*)(gw + off) = f2b(v);
        }
    bf8 a2[2], b2[8];
#pragma unroll
    for (int mb = 0; mb < 2; ++mb){
      int rl = mb * 16 + lo;
      a2[mb] = *(const bf8*)(gw + ((rl >> 1) << 7) + ((rl & 1) << 6)
                                + ((hi << 4) ^ (((rl >> 1) & 3) << 4)));
    }
#pragma unroll
    for (int pb = 0; pb < 8; ++pb)
      b2[pb] = *(const bf8*)(xdtT + (size_t)bhc * 32768 + (pb * 16 + lo) * 256 + sb * 32 + hi * 8);
#pragma unroll
    for (int mb = 0; mb < 2; ++mb)
#pragma unroll
      for (int pb = 0; pb < 8; ++pb)
        accY[mb][pb] = MFMA16(a2[mb], b2[pb], accY[mb][pb]);
  }
  float Dh = Dp[h];
#pragma unroll
  for (int mb = 0; mb < 2; ++mb){
#pragma unroll
    for (int i = 0; i < 4; ++i){
      int lrow = lbase + mb * 16 + hi * 4 + i;
      size_t bl = (size_t)blbase + lrow;
      float gv[8];
      float ss = 0.f;
#pragma unroll
      for (int pb = 0; pb < 8; ++pb){
        int p = pb * 16 + lo;
        float y = accY[mb][pb][i] + Dh * b2f(xf16[bl * 512 + kv * 128 + p]);
        float z = b2f(z16[bl * 2048 + h * 128 + p]);
        float g = y * z * sigm(z);
        gv[pb] = g;
        ss += g * g;
      }
      ss += __shfl_xor(ss, 1);
      ss += __shfl_xor(ss, 2);
      ss += __shfl_xor(ss, 4);
      ss += __shfl_xor(ss, 8);
      float rstd = rsqrtf(ss * (1.f / 128.f) + 1e-5f);
#pragma unroll
      for (int pb = 0; pb < 8; ++pb){
        int p = pb * 16 + lo;
        yn[bl * 2048 + h * 128 + p] = f2b(gv[pb] * rstd * nw[h * 128 + p]);
      }
    }
  }
}

// ---------------------------------------------------------------- launch
extern "C" void kernel_launch(void* const* d_in, const int* in_sizes, int n_in,
                              void* d_out, int out_size, void* d_ws, size_t ws_size,
                              hipStream_t stream){
  const float* hs   = (const float*)d_in[0];
  const float* ipw  = (const float*)d_in[1];
  const float* cw   = (const float*)d_in[2];
  const float* cb   = (const float*)d_in[3];
  const float* dtb  = (const float*)d_in[4];
  const float* alog = (const float*)d_in[5];
  const float* Dp   = (const float*)d_in[6];
  const float* nw   = (const float*)d_in[7];
  const float* opw  = (const float*)d_in[8];
  float* out = (float*)d_out;

  char* base = (char*)d_ws;
  size_t o = 0;
  auto take = [&](size_t n) -> size_t { size_t r = o; o += (n + 255) & ~(size_t)255; return r; };

  // Region A: X16 (K0..K1) -> states16 + prevb (K6..K8)
  size_t offA = take(33554432);
  u16t* X16      = (u16t*)(base + offA);
  u16t* states16 = (u16t*)(base + offA);
  u16t* prevb    = (u16t*)(base + offA + 16777216);
  // Region B: Wp16 (K0..K1) -> BgT + dtv + Acs + dstv + cdec (K3..K8)
  size_t offB = take(21037056);
  u16t*  Wp16 = (u16t*)(base + offB);
  u16t*  BgT  = (u16t*)(base + offB);
  float* dtv  = (float*)(base + offB + 8388608);
  float* Acs  = (float*)(base + offB + 8912896);
  float* dstv = (float*)(base + offB + 9437184);
  float* cdec = (float*)(base + offB + 9961472);
  u16t*  Wo16 = (u16t*)(base + take(8388608));
  u16t*  z16  = (u16t*)(base + take(33554432));
  // Region C: xbc16 (K1..K2) -> yn16 (K8..K9)
  size_t offC = take(50331648);
  u16t* xbc16 = (u16t*)(base + offC);
  u16t* yn16  = (u16t*)(base + offC);
  float* dtraw = (float*)(base + take(524288));
  u16t*  xf16  = (u16t*)(base + take(8388608));
  u16t*  Bg    = (u16t*)(base + take(8388608));
  u16t*  Cgb   = (u16t*)(base + take(33554432));
  u16t*  xdtT  = (u16t*)(base + take(33554432));

  if (ws_size < o) return;  // budget guard

  k_cvt<<<16384, 256, 0, stream>>>(hs, X16, BLROWS * 2048 / 4);
  k_cvt<<<10272, 256, 0, stream>>>(ipw, Wp16, DPROJ * 2048 / 4);
  k_cvt<<<4096, 256, 0, stream>>>(opw, Wo16, 2048 * 2048 / 4);
  k_gemm_in<<<1344, 512, 0, stream>>>(X16, Wp16, z16, xbc16, dtraw);
  k_conv<<<dim3(3, 128, 2), 256, 0, stream>>>(xbc16, cw, cb, xf16, Bg, Cgb);
  k_prep<<<dim3(16, 16, 2), 256, 0, stream>>>(dtraw, dtb, alog, dtv, Acs, dstv, cdec);
  k_repack<<<dim3(16, 16, 2), 256, 0, stream>>>(xf16, dtv, Bg, xdtT, BgT);
  k_states<<<dim3(16, 16, 2), 256, 0, stream>>>(xdtT, dstv, BgT, states16);
  k_scan<<<dim3(16, 2, 16), 256, 0, stream>>>(states16, cdec, prevb);
  k_fin<<<dim3(32, 16, 2), 256, 0, stream>>>(Cgb, Bg, xdtT, prevb, Acs, z16, xf16, Dp, nw, yn16);
  k_gemm_out<<<512, 512, 0, stream>>>(yn16, Wo16, out);
}